// Round 4
// baseline (2243.300 us; speedup 1.0000x reference)
//
#include <hip/hip_runtime.h>

// RCNN forward. conv3x3 layers on MFMA f16 (implicit GEMM), activations in
// [n][y][x][c] f16 layout. conv1 path: register-resident conv both passes.

#define CCH 128
constexpr float KAPPA = 0.001f / 17.0f;

typedef __attribute__((ext_vector_type(8))) _Float16 half8;
typedef __attribute__((ext_vector_type(4))) float f32x4;

union U4 { uint4 v; ushort us[8]; _Float16 h[8]; };

// ---------------------------------------------------------------- zero stats
__global__ __launch_bounds__(256) void zero_stats(float* __restrict__ s) {
    s[threadIdx.x] = 0.f;
}

// ---------------------------------------- conv1 stats: x in regs, co loop
// grid 512 = 128 n x 4 strips of 16 rows; thread = (yl, xg) 4 px.
__global__ __launch_bounds__(256, 2) void conv1_stats2(
    const float* __restrict__ x, const float* __restrict__ w,
    const float* __restrict__ bias, float* __restrict__ stats)
{
    __shared__ float ps[4][128], ps2[4][128];
    const int bid = blockIdx.x;
    const int n = bid & 127;
    const int y0 = (bid >> 7) * 16;
    const int tid = threadIdx.x;
    const int yl = tid >> 4, xg = tid & 15;
    const int y = y0 + yl, x0 = xg * 4;
    const int wv = tid >> 6, lane = tid & 63;

    const float* xn = x + (size_t)n * 3 * 4096;
    float xr[3][5][8];
    #pragma unroll
    for (int ci = 0; ci < 3; ++ci)
        #pragma unroll
        for (int ky = 0; ky < 5; ++ky) {
            int gy = y + ky - 2;
            const float* row = xn + ci * 4096 + gy * 64;
            bool yok = (unsigned)gy < 64u;
            #pragma unroll
            for (int j = 0; j < 8; ++j) {
                int gx = x0 - 2 + j;
                xr[ci][ky][j] = (yok && (unsigned)gx < 64u) ? row[gx] : 0.f;
            }
        }

    for (int co = 0; co < 128; ++co) {
        const float* wc = w + co * 75;
        const float bc = bias[co];
        float a[4] = {bc, bc, bc, bc};
        #pragma unroll
        for (int ci = 0; ci < 3; ++ci)
            #pragma unroll
            for (int ky = 0; ky < 5; ++ky)
                #pragma unroll
                for (int kx = 0; kx < 5; ++kx) {
                    float wvv = wc[ci * 25 + ky * 5 + kx];
                    #pragma unroll
                    for (int j = 0; j < 4; ++j) a[j] += xr[ci][ky][j + kx] * wvv;
                }
        float s = a[0] + a[1] + a[2] + a[3];
        float s2 = a[0]*a[0] + a[1]*a[1] + a[2]*a[2] + a[3]*a[3];
        #pragma unroll
        for (int o = 1; o < 64; o <<= 1) {
            s  += __shfl_xor(s, o, 64);
            s2 += __shfl_xor(s2, o, 64);
        }
        if (lane == 0) { ps[wv][co] = s; ps2[wv][co] = s2; }
    }
    __syncthreads();
    if (tid < 128) {
        float A = ps[0][tid] + ps[1][tid] + ps[2][tid] + ps[3][tid];
        float B = ps2[0][tid] + ps2[1][tid] + ps2[2][tid] + ps2[3][tid];
        atomicAdd(&stats[tid], A);
        atomicAdd(&stats[tid + 128], B);
    }
}

// --------------------------------------------------------------- bn finalize
__global__ __launch_bounds__(128) void bn_finalize(
    const float* __restrict__ stats, const float* __restrict__ g,
    const float* __restrict__ b, float* __restrict__ scsh)
{
    const int c = threadIdx.x;
    const float M = 128.f * 4096.f;
    float mean = stats[c] / M;
    float var = stats[c + 128] / M - mean * mean;
    float rstd = rsqrtf(var + 1e-5f);
    float sc = g[c] * rstd;
    scsh[c] = sc;
    scsh[c + 128] = b[c] - mean * sc;
}

// ------------- conv1 + BN + relu + maxpool(3,2,1): x in regs, h via LDS
// grid 512 = 128 n x 4 strips (8 pooled rows each). 320 threads:
// conv tasks 0..271 = 17 h-rows x 16 xgroups (incl. top halo row);
// pool tasks 0..255 = 8 pooled rows x 32 cols.
__global__ __launch_bounds__(320, 2) void conv1_pool2(
    const float* __restrict__ x, const float* __restrict__ w,
    const float* __restrict__ bias, const float* __restrict__ scsh,
    _Float16* __restrict__ out)
{
    __shared__ float hb[8][17][68];       // 37 KB
    const int bid = blockIdx.x;
    const int n = bid & 127;
    const int strip = bid >> 7;
    const int tid = threadIdx.x;
    const bool cactive = tid < 272;
    const int yl = tid >> 4, xg = tid & 15;
    const int hy = strip * 16 - 1 + yl;           // [-1, 63] for tasks
    const int x0 = xg * 4;
    const bool hvalid = cactive && (unsigned)hy < 64u;

    float xr[3][5][8];
    const float* xn = x + (size_t)n * 3 * 4096;
    #pragma unroll
    for (int ci = 0; ci < 3; ++ci)
        #pragma unroll
        for (int ky = 0; ky < 5; ++ky) {
            int gy = hy + ky - 2;
            bool yok = hvalid && (unsigned)gy < 64u;
            const float* row = xn + ci * 4096 + gy * 64;
            #pragma unroll
            for (int j = 0; j < 8; ++j) {
                int gx = x0 - 2 + j;
                xr[ci][ky][j] = (yok && (unsigned)gx < 64u) ? row[gx] : 0.f;
            }
        }

    const int oy = (tid & 255) >> 5, ox = tid & 31;
    const bool pactive = tid < 256;
    _Float16* ob = out + ((size_t)n * 1024 + (size_t)(strip * 8 + oy) * 32 + ox) * 128;

    for (int cog = 0; cog < 16; ++cog) {
        __syncthreads();                  // hb free (consumed by prev pool)
        #pragma unroll 2
        for (int j8 = 0; j8 < 8; ++j8) {
            const int co = cog * 8 + j8;
            const float* wc = w + co * 75;
            const float bc = bias[co];
            float a[4] = {bc, bc, bc, bc};
            #pragma unroll
            for (int ci = 0; ci < 3; ++ci)
                #pragma unroll
                for (int ky = 0; ky < 5; ++ky)
                    #pragma unroll
                    for (int kx = 0; kx < 5; ++kx) {
                        float wvv = wc[ci * 25 + ky * 5 + kx];
                        #pragma unroll
                        for (int j = 0; j < 4; ++j) a[j] += xr[ci][ky][j + kx] * wvv;
                    }
            const float sc = scsh[co], sh = scsh[co + 128];
            float4 hv;
            hv.x = hvalid ? fmaxf(a[0] * sc + sh, 0.f) : 0.f;
            hv.y = hvalid ? fmaxf(a[1] * sc + sh, 0.f) : 0.f;
            hv.z = hvalid ? fmaxf(a[2] * sc + sh, 0.f) : 0.f;
            hv.w = hvalid ? fmaxf(a[3] * sc + sh, 0.f) : 0.f;
            if (cactive) *(float4*)&hb[j8][yl][x0] = hv;
        }
        __syncthreads();
        if (pactive) {
            U4 pk;
            #pragma unroll
            for (int j8 = 0; j8 < 8; ++j8) {
                float m = 0.f;
                #pragma unroll
                for (int dy = -1; dy <= 1; ++dy) {
                    int ly = 2 * oy + 1 + dy;     // [0,16] always in range
                    #pragma unroll
                    for (int dx = -1; dx <= 1; ++dx) {
                        int ix = 2 * ox + dx;
                        if ((unsigned)ix < 64u) m = fmaxf(m, hb[j8][ly][ix]);
                    }
                }
                pk.h[j8] = (_Float16)m;
            }
            *(uint4*)&ob[cog * 8] = pk.v;
        }
    }
}

// --------------------------------------- weight convert fp32 [co][ci][3][3]
//                                      -> f16 [tap][co][ci]
__global__ __launch_bounds__(256) void wcvt(const float* __restrict__ wsrc,
                                            _Float16* __restrict__ wdst)
{
    const int idx = blockIdx.x * 256 + threadIdx.x;   // 147456
    const int t = idx >> 14;
    const int rem = idx & 16383;
    const int co = rem >> 7;
    const int ci = rem & 127;
    wdst[idx] = (_Float16)wsrc[(co * 128 + ci) * 9 + t];
}

// --------------------------------------------- conv3x3 MFMA (128->128, pad 1)
template<int H, bool ADD_F>
__global__ __launch_bounds__(256, 2) void conv3(
    const _Float16* __restrict__ in, const _Float16* __restrict__ wb,
    const float* __restrict__ bias, const _Float16* __restrict__ fadd,
    _Float16* __restrict__ outp)
{
    constexpr int W = H, HW = H * W;
    constexpr int XP = W + 2;
    constexpr int PITCH = 40;
    constexpr int ROWS = 10;
    constexpr int PTN = (H == 32) ? 4 : 2;
    constexpr int NPIX = PTN * 16;
    constexpr int STAGE = ROWS * XP * PITCH;
    constexpr int TASKS = ROWS * W * 4;
    constexpr int NIT = (TASKS + 255) / 256;
    constexpr int LOG4W = (H == 32) ? 7 : 6;
    constexpr int LDSF = 4 * NPIX * 36;

    __shared__ float ldsf[LDSF];
    _Float16* xs = (_Float16*)ldsf;

    const int bid = blockIdx.x;
    const int slot = bid >> 3;
    const int n = (bid & 7) + 8 * (slot & 15);
    const int y0 = (slot >> 4) * 8;
    const int tid = threadIdx.x;
    const int w = tid >> 6, l = tid & 63;
    const int l15 = l & 15, lg = l >> 4;

    for (int i = tid; i < STAGE / 2; i += 256) ((uint*)xs)[i] = 0;

    f32x4 acc[8][PTN];
    #pragma unroll
    for (int cot = 0; cot < 8; ++cot) {
        f32x4 bv = {0.f, 0.f, 0.f, 0.f};
        if constexpr (!ADD_F) bv = *(const f32x4*)&bias[cot * 16 + lg * 4];
        #pragma unroll
        for (int pt = 0; pt < PTN; ++pt) acc[cot][pt] = bv;
    }

    const _Float16* inb = in + (size_t)n * HW * 128;
    uint4 stg[NIT];

    auto issue = [&](int c0) {
        #pragma unroll
        for (int i = 0; i < NIT; ++i) {
            int t = tid + i * 256;
            uint4 v = {0u, 0u, 0u, 0u};
            if (TASKS % 256 == 0 || t < TASKS) {
                int g = t & 3, xx = (t >> 2) & (W - 1), yl = t >> LOG4W;
                int gy = y0 - 1 + yl;
                if ((unsigned)gy < (unsigned)H)
                    v = *(const uint4*)&inb[((size_t)(gy * W + xx)) * 128 + c0 + g * 8];
            }
            stg[i] = v;
        }
    };
    auto commit = [&]() {
        #pragma unroll
        for (int i = 0; i < NIT; ++i) {
            int t = tid + i * 256;
            if (TASKS % 256 == 0 || t < TASKS) {
                int g = t & 3, xx = (t >> 2) & (W - 1), yl = t >> LOG4W;
                *(uint4*)&xs[(yl * XP + xx + 1) * PITCH + g * 8] = stg[i];
            }
        }
    };

    int bofs[PTN];
    #pragma unroll
    for (int pt = 0; pt < PTN; ++pt) {
        int row_l = 2 * w + ((H == 32) ? (pt >> 1) : pt);
        int xb = ((H == 32) ? (pt & 1) * 16 : 0) + l15;
        bofs[pt] = ((row_l + 1) * XP + xb + 1) * PITCH + lg * 8;
    }
    const _Float16* wl = wb + l15 * 128 + lg * 8;

    issue(0);
    for (int cc = 0; cc < 4; ++cc) {
        const int c0 = cc * 32;
        __syncthreads();
        commit();
        if (cc < 3) issue(c0 + 32);
        __syncthreads();
        #pragma unroll
        for (int ky = -1; ky <= 1; ++ky)
            #pragma unroll
            for (int kx = -1; kx <= 1; ++kx) {
                const int t9 = (ky + 1) * 3 + (kx + 1);
                half8 bf[PTN];
                #pragma unroll
                for (int pt = 0; pt < PTN; ++pt)
                    bf[pt] = *(const half8*)&xs[bofs[pt] + (ky * XP + kx) * PITCH];
                const _Float16* wt = wl + t9 * 16384 + c0;
                #pragma unroll
                for (int coh = 0; coh < 2; ++coh) {
                    half8 av[4];
                    #pragma unroll
                    for (int j = 0; j < 4; ++j)
                        av[j] = *(const half8*)&wt[(coh * 4 + j) * 2048];
                    #pragma unroll
                    for (int j = 0; j < 4; ++j)
                        #pragma unroll
                        for (int pt = 0; pt < PTN; ++pt)
                            acc[coh * 4 + j][pt] = __builtin_amdgcn_mfma_f32_16x16x32_f16(
                                av[j], bf[pt], acc[coh * 4 + j][pt], 0, 0, 0);
                }
            }
    }

    __syncthreads();
    float* bw = ldsf + w * (NPIX * 36);
    const int pix = (H == 32) ? l : (l & 31);
    const int sub = (H == 32) ? 0 : (l >> 5);
    constexpr int NCO = (H == 32) ? 32 : 16;
    const int row_l = 2 * w + ((H == 32) ? (pix >> 5) : (pix >> 4));
    const int xo = pix & (W - 1);
    const size_t gbase = ((size_t)n * HW + (size_t)(y0 + row_l) * W + xo) * 128;

    #pragma unroll
    for (int q = 0; q < 4; ++q) {
        #pragma unroll
        for (int j = 0; j < 2; ++j)
            #pragma unroll
            for (int pt = 0; pt < PTN; ++pt) {
                int p = pt * 16 + l15;
                *(f32x4*)&bw[p * 36 + j * 16 + lg * 4] = acc[2 * q + j][pt];
            }
        const int cofs = q * 32 + sub * 16;
        #pragma unroll
        for (int j8 = 0; j8 < NCO / 8; ++j8) {
            f32x4 v0 = *(const f32x4*)&bw[pix * 36 + sub * 16 + j8 * 8];
            f32x4 v1 = *(const f32x4*)&bw[pix * 36 + sub * 16 + j8 * 8 + 4];
            float vv[8];
            #pragma unroll
            for (int i = 0; i < 4; ++i) { vv[i] = v0[i]; vv[4 + i] = v1[i]; }
            if constexpr (ADD_F) {
                U4 fv; fv.v = *(const uint4*)&fadd[gbase + cofs + j8 * 8];
                #pragma unroll
                for (int i = 0; i < 8; ++i) vv[i] += (float)fv.h[i];
            }
            U4 o;
            #pragma unroll
            for (int i = 0; i < 8; ++i) o.h[i] = (_Float16)vv[i];
            *(uint4*)&outp[gbase + cofs + j8 * 8] = o.v;
        }
    }
}

// ------------------------------------------------------------------- LRN
__global__ __launch_bounds__(256) void lrn_k(const _Float16* __restrict__ s,
                                             _Float16* __restrict__ r)
{
    const int idx = blockIdx.x * 256 + threadIdx.x;
    const _Float16* sb = s + (size_t)idx * 128;
    _Float16* rb = r + (size_t)idx * 128;
    U4 sv[16];
    #pragma unroll
    for (int i = 0; i < 16; ++i) sv[i].v = ((const uint4*)sb)[i];
    float ring[17], zr[9], wsum = 0.f;
    #pragma unroll
    for (int i = 0; i < 17; ++i) ring[i] = 0.f;
    #pragma unroll
    for (int i = 0; i < 9; ++i) zr[i] = 0.f;
    U4 ob;
    #pragma unroll
    for (int c = 0; c < 136; ++c) {
        float z = 0.f;
        if (c < 128) {
            float v = (float)sv[c >> 3].h[c & 7];
            z = v > 0.f ? v : 0.f;
        }
        float zz = z * z;
        wsum += zz - ring[c % 17];
        ring[c % 17] = zz;
        zr[c % 9] = z;
        if (c >= 8) {
            int o = c - 8;
            float p75 = exp2f(-0.75f * log2f(wsum * KAPPA + 1.f));
            ob.h[o & 7] = (_Float16)(zr[(c + 1) % 9] * p75);
            if ((o & 7) == 7) ((uint4*)rb)[o >> 3] = ob.v;
        }
    }
}

// ------------------------------- maxpool(3,2,1) 32 -> 16, 8 channels/thread
__global__ __launch_bounds__(256) void pool32v(const _Float16* __restrict__ in,
                                               _Float16* __restrict__ out)
{
    const int idx = blockIdx.x * 256 + threadIdx.x;   // 524288
    const int cg = idx & 15;
    const int opix = (idx >> 4) & 255;
    const int n = idx >> 12;
    const int oy = opix >> 4, ox = opix & 15;
    const _Float16* ib = in + (size_t)n * 1024 * 128 + cg * 8;
    float m[8] = {0.f, 0.f, 0.f, 0.f, 0.f, 0.f, 0.f, 0.f};
    #pragma unroll
    for (int dy = -1; dy <= 1; ++dy) {
        int iy = 2 * oy + dy;
        if ((unsigned)iy >= 32u) continue;
        #pragma unroll
        for (int dx = -1; dx <= 1; ++dx) {
            int ix = 2 * ox + dx;
            if ((unsigned)ix >= 32u) continue;
            U4 v; v.v = *(const uint4*)&ib[(size_t)(iy * 32 + ix) * 128];
            #pragma unroll
            for (int i = 0; i < 8; ++i) m[i] = fmaxf(m[i], (float)v.h[i]);
        }
    }
    U4 o;
    #pragma unroll
    for (int i = 0; i < 8; ++i) o.h[i] = (_Float16)m[i];
    *(uint4*)&out[((size_t)n * 256 + opix) * 128 + cg * 8] = o.v;
}

// ------------- maxpool(3,2,0)+global max == max over [0,15)^2, 8 ch/thread
__global__ __launch_bounds__(256) void gmax2(const _Float16* __restrict__ in,
                                             float* __restrict__ g)
{
    const int idx = blockIdx.x * 256 + threadIdx.x;   // 2048
    const int c8 = idx & 15;
    const int n = idx >> 4;
    const _Float16* ib = in + (size_t)n * 256 * 128 + c8 * 8;
    float m[8] = {0.f, 0.f, 0.f, 0.f, 0.f, 0.f, 0.f, 0.f};
    for (int y = 0; y < 15; ++y)
        #pragma unroll
        for (int x = 0; x < 15; ++x) {
            U4 v; v.v = *(const uint4*)&ib[(size_t)(y * 16 + x) * 128];
            #pragma unroll
            for (int i = 0; i < 8; ++i) m[i] = fmaxf(m[i], (float)v.h[i]);
        }
    float* gb = g + n * 128 + c8 * 8;
    *(float4*)&gb[0] = {m[0], m[1], m[2], m[3]};
    *(float4*)&gb[4] = {m[4], m[5], m[6], m[7]};
}

// ------------------------------------------------------------------- MLP
__global__ __launch_bounds__(256) void mlp_k(
    const float* __restrict__ g, const float* __restrict__ w,
    const float* __restrict__ b, float* __restrict__ out)
{
    const int idx = blockIdx.x * 256 + threadIdx.x;
    if (idx >= 1280) return;
    const int n = idx / 10, k = idx - n * 10;
    float acc = b[k];
    for (int c = 0; c < CCH; ++c) acc += g[n * CCH + c] * w[k * CCH + c];
    out[idx] = acc;
}

// ==================================================================== launch
extern "C" void kernel_launch(void* const* d_in, const int* in_sizes, int n_in,
                              void* d_out, int out_size, void* d_ws, size_t ws_size,
                              hipStream_t stream)
{
    const float* x   = (const float*)d_in[0];
    const float* w1  = (const float*)d_in[1];
    const float* b1  = (const float*)d_in[2];
    const float* bng = (const float*)d_in[3];
    const float* bnb = (const float*)d_in[4];
    const float* fw[4] = {(const float*)d_in[5],  (const float*)d_in[8],
                          (const float*)d_in[11], (const float*)d_in[14]};
    const float* fb[4] = {(const float*)d_in[6],  (const float*)d_in[9],
                          (const float*)d_in[12], (const float*)d_in[15]};
    const float* rw[4] = {(const float*)d_in[7],  (const float*)d_in[10],
                          (const float*)d_in[13], (const float*)d_in[16]};
    const float* mw = (const float*)d_in[17];
    const float* mb = (const float*)d_in[18];
    float* out = (float*)d_out;

    _Float16* ws16 = (_Float16*)d_ws;
    _Float16* A32  = ws16;                       // [128][32][32][128]
    _Float16* F32  = ws16 + 16777216;
    _Float16* S32  = ws16 + 2 * 16777216;
    _Float16* A16  = ws16 + 3 * 16777216;        // [128][16][16][128]
    _Float16* F16b = A16 + 4194304;
    _Float16* S16b = A16 + 2 * 4194304;
    _Float16* Wb   = A16 + 3 * 4194304;          // 8 layers x [9][128][128]
    float* stats = (float*)(Wb + 8 * 147456);
    float* scsh  = stats + 256;
    float* gm    = scsh + 256;

    zero_stats<<<1, 256, 0, stream>>>(stats);
    conv1_stats2<<<512, 256, 0, stream>>>(x, w1, b1, stats);
    bn_finalize<<<1, 128, 0, stream>>>(stats, bng, bnb, scsh);
    conv1_pool2<<<512, 320, 0, stream>>>(x, w1, b1, scsh, A32);

    const float* lw[8] = {fw[0], rw[0], fw[1], rw[1], fw[2], rw[2], fw[3], rw[3]};
    for (int i = 0; i < 8; ++i)
        wcvt<<<576, 256, 0, stream>>>(lw[i], Wb + i * 147456);

    for (int s = 0; s < 2; ++s) {
        conv3<32, false><<<512, 256, 0, stream>>>(A32, Wb + (2*s) * 147456, fb[s], nullptr, F32);
        lrn_k<<<512, 256, 0, stream>>>(F32, A32);
        for (int it = 0; it < 3; ++it) {
            conv3<32, true><<<512, 256, 0, stream>>>(A32, Wb + (2*s+1) * 147456, nullptr, F32, S32);
            lrn_k<<<512, 256, 0, stream>>>(S32, A32);
        }
    }
    pool32v<<<2048, 256, 0, stream>>>(A32, A16);
    for (int s = 2; s < 4; ++s) {
        conv3<16, false><<<256, 256, 0, stream>>>(A16, Wb + (2*s) * 147456, fb[s], nullptr, F16b);
        lrn_k<<<128, 256, 0, stream>>>(F16b, A16);
        for (int it = 0; it < 3; ++it) {
            conv3<16, true><<<256, 256, 0, stream>>>(A16, Wb + (2*s+1) * 147456, nullptr, F16b, S16b);
            lrn_k<<<128, 256, 0, stream>>>(S16b, A16);
        }
    }
    gmax2<<<8, 256, 0, stream>>>(A16, gm);
    mlp_k<<<5, 256, 0, stream>>>(gm, mw, mb, out);
}

// Round 5
// 1811.864 us; speedup vs baseline: 1.2381x; 1.2381x over previous
//
#include <hip/hip_runtime.h>

// RCNN forward. conv3x3 on MFMA f16 (implicit GEMM) with FUSED banded-LRN
// epilogue; activations [n][y][x][c] f16. conv1: register-pinned fp32 conv
// (stats pass + BN/pool pass), exact-256-task strips + partial-max fix-up.

#define CCH 128
constexpr float KAPPA = 0.001f / 17.0f;

typedef __attribute__((ext_vector_type(8))) _Float16 half8;
typedef __attribute__((ext_vector_type(4))) float f32x4;

union U4 { uint4 v; ushort us[8]; _Float16 h[8]; };
union U2 { ushort4 u; _Float16 h[4]; };

// ---------------------------------------------------------------- zero stats
__global__ __launch_bounds__(256) void zero_stats(float* __restrict__ s) {
    s[threadIdx.x] = 0.f;
}

// -------------------------------------------------------- conv1 helpers
// Load 3ci x 5ky x 8x patch into regs and PIN them (defeat load-sinking).
__device__ __forceinline__ void load_pin_xr(const float* __restrict__ xn,
                                            int y, int x0, float xr[3][5][8])
{
    #pragma unroll
    for (int ci = 0; ci < 3; ++ci)
        #pragma unroll
        for (int ky = 0; ky < 5; ++ky) {
            int gy = y + ky - 2;
            bool yok = (unsigned)gy < 64u;
            const float* row = xn + ci * 4096 + gy * 64;
            #pragma unroll
            for (int j = 0; j < 8; ++j) {
                int gx = x0 - 2 + j;
                xr[ci][ky][j] = (yok && (unsigned)gx < 64u) ? row[gx] : 0.f;
            }
        }
    #pragma unroll
    for (int ci = 0; ci < 3; ++ci)
        #pragma unroll
        for (int ky = 0; ky < 5; ++ky)
            #pragma unroll
            for (int j = 0; j < 8; ++j)
                asm volatile("" : "+v"(xr[ci][ky][j]));
}

__device__ __forceinline__ void conv_co(const float xr[3][5][8],
                                        const float* __restrict__ wc,
                                        float bc, float a[4])
{
    a[0] = a[1] = a[2] = a[3] = bc;
    #pragma unroll
    for (int ci = 0; ci < 3; ++ci)
        #pragma unroll
        for (int ky = 0; ky < 5; ++ky)
            #pragma unroll
            for (int kx = 0; kx < 5; ++kx) {
                float wv = wc[ci * 25 + ky * 5 + kx];
                #pragma unroll
                for (int j = 0; j < 4; ++j) a[j] += xr[ci][ky][j + kx] * wv;
            }
}

// ---------------------------------------- conv1 stats: x pinned in regs
// grid 512 = 128 n x 4 strips of 16 rows; thread = (yl, xg) 4 px.
__global__ __launch_bounds__(256, 2) void conv1_stats3(
    const float* __restrict__ x, const float* __restrict__ w,
    const float* __restrict__ bias, float* __restrict__ stats)
{
    __shared__ float ps[4][128], ps2[4][128];
    const int bid = blockIdx.x;
    const int n = bid & 127;
    const int y0 = (bid >> 7) * 16;
    const int tid = threadIdx.x;
    const int yl = tid >> 4, xg = tid & 15;
    const int wv = tid >> 6, lane = tid & 63;

    const float* xn = x + (size_t)n * 3 * 4096;
    float xr[3][5][8];
    load_pin_xr(xn, y0 + yl, xg * 4, xr);

    for (int co = 0; co < 128; ++co) {
        float a[4];
        conv_co(xr, w + co * 75, bias[co], a);
        float s = a[0] + a[1] + a[2] + a[3];
        float s2 = a[0]*a[0] + a[1]*a[1] + a[2]*a[2] + a[3]*a[3];
        #pragma unroll
        for (int o = 1; o < 64; o <<= 1) {
            s  += __shfl_xor(s, o, 64);
            s2 += __shfl_xor(s2, o, 64);
        }
        if (lane == 0) { ps[wv][co] = s; ps2[wv][co] = s2; }
    }
    __syncthreads();
    if (tid < 128) {
        float A = ps[0][tid] + ps[1][tid] + ps[2][tid] + ps[3][tid];
        float B = ps2[0][tid] + ps2[1][tid] + ps2[2][tid] + ps2[3][tid];
        atomicAdd(&stats[tid], A);
        atomicAdd(&stats[tid + 128], B);
    }
}

// --------------------------------------------------------------- bn finalize
__global__ __launch_bounds__(128) void bn_finalize(
    const float* __restrict__ stats, const float* __restrict__ g,
    const float* __restrict__ b, float* __restrict__ scsh)
{
    const int c = threadIdx.x;
    const float M = 128.f * 4096.f;
    float mean = stats[c] / M;
    float var = stats[c + 128] / M - mean * mean;
    float rstd = rsqrtf(var + 1e-5f);
    float sc = g[c] * rstd;
    scsh[c] = sc;
    scsh[c + 128] = b[c] - mean * sc;
}

// --------- conv1 + BN + relu + maxpool(3,2,1): x pinned in regs, h via LDS
// grid 512 = 128 n x 4 strips of 16 h-rows (8 pooled rows). Pooled row 8s
// lacks its top halo row (16s-1): that row's 3-col maxes go to Pp from the
// strip that OWNS it (local row 15); pool_fix combines.
__global__ __launch_bounds__(256, 2) void conv1_pool3(
    const float* __restrict__ x, const float* __restrict__ w,
    const float* __restrict__ bias, const float* __restrict__ scsh,
    _Float16* __restrict__ out, _Float16* __restrict__ Pp)
{
    __shared__ float hb[8][16][68];
    const int bid = blockIdx.x;
    const int n = bid & 127;
    const int s = bid >> 7;
    const int tid = threadIdx.x;
    const int yl = tid >> 4, xg = tid & 15;

    const float* xn = x + (size_t)n * 3 * 4096;
    float xr[3][5][8];
    load_pin_xr(xn, s * 16 + yl, xg * 4, xr);

    const int oyl = tid >> 5, ox = tid & 31;
    _Float16* ob = out + ((size_t)n * 1024 + (size_t)(s * 8 + oyl) * 32 + ox) * 128;

    for (int cog = 0; cog < 16; ++cog) {
        __syncthreads();                  // hb consumed by previous pool
        #pragma unroll 2
        for (int j8 = 0; j8 < 8; ++j8) {
            const int co = cog * 8 + j8;
            float a[4];
            conv_co(xr, w + co * 75, bias[co], a);
            const float sc = scsh[co], sh = scsh[co + 128];
            float4 hv;
            hv.x = fmaxf(a[0] * sc + sh, 0.f);
            hv.y = fmaxf(a[1] * sc + sh, 0.f);
            hv.z = fmaxf(a[2] * sc + sh, 0.f);
            hv.w = fmaxf(a[3] * sc + sh, 0.f);
            *(float4*)&hb[j8][yl][xg * 4] = hv;
        }
        __syncthreads();
        U4 pk;
        #pragma unroll
        for (int j8 = 0; j8 < 8; ++j8) {
            float m = 0.f;
            #pragma unroll
            for (int dy = -1; dy <= 1; ++dy) {
                int ly = 2 * oyl + dy;
                if (ly < 0) continue;     // top halo -> pool_fix
                #pragma unroll
                for (int dx = -1; dx <= 1; ++dx) {
                    int ix = 2 * ox + dx;
                    if ((unsigned)ix < 64u) m = fmaxf(m, hb[j8][ly][ix]);
                }
            }
            pk.h[j8] = (_Float16)m;
        }
        *(uint4*)&ob[cog * 8] = pk.v;
        if (s < 3 && tid < 32) {          // contribution of local row 15 to
            U4 pw;                        // next strip's pooled row 8(s+1)
            #pragma unroll
            for (int j8 = 0; j8 < 8; ++j8) {
                float m = 0.f;
                #pragma unroll
                for (int dx = -1; dx <= 1; ++dx) {
                    int ix = 2 * tid + dx;
                    if ((unsigned)ix < 64u) m = fmaxf(m, hb[j8][15][ix]);
                }
                pw.h[j8] = (_Float16)m;
            }
            *(uint4*)&Pp[(((size_t)n * 3 + s) * 32 + tid) * 128 + cog * 8] = pw.v;
        }
    }
}

// ----------------------------- combine halo partials into pooled rows 8,16,24
__global__ __launch_bounds__(256) void pool_fix(const _Float16* __restrict__ P,
                                                _Float16* __restrict__ A)
{
    const int idx = blockIdx.x * 256 + threadIdx.x;   // 196608
    const int cg = idx & 15;
    int t = idx >> 4;
    const int ox = t & 31; t >>= 5;
    const int sp = t % 3;                 // strip 0..2 -> pooled row 8(sp+1)
    const int n = t / 3;
    const _Float16* pp = P + (((size_t)n * 3 + sp) * 32 + ox) * 128 + cg * 8;
    _Float16* ap = A + ((size_t)n * 1024 + (size_t)(8 * (sp + 1)) * 32 + ox) * 128 + cg * 8;
    U4 a, b;
    a.v = *(const uint4*)ap;
    b.v = *(const uint4*)pp;
    #pragma unroll
    for (int i = 0; i < 8; ++i)
        if ((float)b.h[i] > (float)a.h[i]) a.h[i] = b.h[i];
    *(uint4*)ap = a.v;
}

// --------------------------------------- weight convert fp32 [co][ci][3][3]
//                                      -> f16 [tap][co][ci]
__global__ __launch_bounds__(256) void wcvt(const float* __restrict__ wsrc,
                                            _Float16* __restrict__ wdst)
{
    const int idx = blockIdx.x * 256 + threadIdx.x;   // 147456
    const int t = idx >> 14;
    const int rem = idx & 16383;
    const int co = rem >> 7;
    const int ci = rem & 127;
    wdst[idx] = (_Float16)wsrc[(co * 128 + ci) * 9 + t];
}

// ------------------------ conv3x3 MFMA (128->128, pad 1) + FUSED banded LRN
// block = 1 image x 8-row strip, 4 waves; wave = all 128 co x NPIX px.
// Epilogue: acc -> LDS [px][128co] f16 (XOR swizzle) -> per-lane LRN ring ->
// A out; f-iters also write F, r-iters read F (f-add before relu).
template<int H, bool ADD_F>
__global__ __launch_bounds__(256, 2) void conv3f(
    const _Float16* __restrict__ in, const _Float16* __restrict__ wb,
    const float* __restrict__ bias, _Float16* __restrict__ fbuf,
    _Float16* __restrict__ outp)
{
    constexpr int W = H, HW = H * W;
    constexpr int XP = W + 2;
    constexpr int PITCH = 40;                  // f16 per pixel slot (32 used)
    constexpr int ROWS = 10;
    constexpr int PTN = (H == 32) ? 4 : 2;
    constexpr int NPIX = PTN * 16;
    constexpr int STAGE = ROWS * XP * PITCH;   // f16 count (<= LDSH)
    constexpr int TASKS = ROWS * W * 4;
    constexpr int NIT = (TASKS + 255) / 256;
    constexpr int LOG4W = (H == 32) ? 7 : 6;
    constexpr int LDSH = 4 * NPIX * 128;       // bounce: 4 waves x NPIX x 128 f16

    __shared__ _Float16 xs[LDSH];

    const int bid = blockIdx.x;
    const int slot = bid >> 3;
    const int n = (bid & 7) + 8 * (slot & 15);
    const int y0 = (slot >> 4) * 8;
    const int tid = threadIdx.x;
    const int w = tid >> 6, l = tid & 63;
    const int l15 = l & 15, lg = l >> 4;

    for (int i = tid; i < STAGE / 2; i += 256) ((uint*)xs)[i] = 0;

    f32x4 acc[8][PTN];
    #pragma unroll
    for (int cot = 0; cot < 8; ++cot) {
        f32x4 bv = {0.f, 0.f, 0.f, 0.f};
        if constexpr (!ADD_F) bv = *(const f32x4*)&bias[cot * 16 + lg * 4];
        #pragma unroll
        for (int pt = 0; pt < PTN; ++pt) acc[cot][pt] = bv;
    }

    const _Float16* inb = in + (size_t)n * HW * 128;
    uint4 stg[NIT];

    auto issue = [&](int c0) {
        #pragma unroll
        for (int i = 0; i < NIT; ++i) {
            int t = tid + i * 256;
            uint4 v = {0u, 0u, 0u, 0u};
            if (TASKS % 256 == 0 || t < TASKS) {
                int g = t & 3, xx = (t >> 2) & (W - 1), yl = t >> LOG4W;
                int gy = y0 - 1 + yl;
                if ((unsigned)gy < (unsigned)H)
                    v = *(const uint4*)&inb[((size_t)(gy * W + xx)) * 128 + c0 + g * 8];
            }
            stg[i] = v;
        }
    };
    auto commit = [&]() {
        #pragma unroll
        for (int i = 0; i < NIT; ++i) {
            int t = tid + i * 256;
            if (TASKS % 256 == 0 || t < TASKS) {
                int g = t & 3, xx = (t >> 2) & (W - 1), yl = t >> LOG4W;
                *(uint4*)&xs[(yl * XP + xx + 1) * PITCH + g * 8] = stg[i];
            }
        }
    };

    int bofs[PTN];
    #pragma unroll
    for (int pt = 0; pt < PTN; ++pt) {
        int row_l = 2 * w + ((H == 32) ? (pt >> 1) : pt);
        int xb = ((H == 32) ? (pt & 1) * 16 : 0) + l15;
        bofs[pt] = ((row_l + 1) * XP + xb + 1) * PITCH + lg * 8;
    }
    const _Float16* wl = wb + l15 * 128 + lg * 8;

    issue(0);
    for (int cc = 0; cc < 4; ++cc) {
        const int c0 = cc * 32;
        __syncthreads();
        commit();
        if (cc < 3) issue(c0 + 32);
        __syncthreads();
        #pragma unroll
        for (int ky = -1; ky <= 1; ++ky)
            #pragma unroll
            for (int kx = -1; kx <= 1; ++kx) {
                const int t9 = (ky + 1) * 3 + (kx + 1);
                half8 bf[PTN];
                #pragma unroll
                for (int pt = 0; pt < PTN; ++pt)
                    bf[pt] = *(const half8*)&xs[bofs[pt] + (ky * XP + kx) * PITCH];
                const _Float16* wt = wl + t9 * 16384 + c0;
                #pragma unroll
                for (int coh = 0; coh < 2; ++coh) {
                    half8 av[4];
                    #pragma unroll
                    for (int j = 0; j < 4; ++j)
                        av[j] = *(const half8*)&wt[(coh * 4 + j) * 2048];
                    #pragma unroll
                    for (int j = 0; j < 4; ++j)
                        #pragma unroll
                        for (int pt = 0; pt < PTN; ++pt)
                            acc[coh * 4 + j][pt] = __builtin_amdgcn_mfma_f32_16x16x32_f16(
                                av[j], bf[pt], acc[coh * 4 + j][pt], 0, 0, 0);
                }
            }
    }

    // ---------------- fused epilogue: bounce -> per-pixel LRN ----------------
    __syncthreads();                           // xs (stage) no longer needed
    _Float16* bx = xs + w * (NPIX * 128);
    #pragma unroll
    for (int a = 0; a < 8; ++a)
        #pragma unroll
        for (int pt = 0; pt < PTN; ++pt) {
            const int wpx = pt * 16 + l15;
            const int col = (a * 16 + lg * 4) ^ ((wpx & 7) * 8);
            U2 pk;
            pk.h[0] = (_Float16)acc[a][pt][0];
            pk.h[1] = (_Float16)acc[a][pt][1];
            pk.h[2] = (_Float16)acc[a][pt][2];
            pk.h[3] = (_Float16)acc[a][pt][3];
            *(ushort4*)&bx[wpx * 128 + col] = pk.u;
        }
    __syncthreads();

    if (H == 32 || l < 32) {
        const int px = l & (NPIX - 1);
        const int p3 = px & 7;
        U4 sv[16];
        #pragma unroll
        for (int g = 0; g < 16; ++g)
            sv[g].v = *(const uint4*)&bx[px * 128 + ((g ^ p3) * 8)];

        const int row_l = 2 * w + ((H == 32) ? (px >> 5) : (px >> 4));
        const int xo = px & (W - 1);
        const size_t gbase = ((size_t)n * HW + (size_t)(y0 + row_l) * W + xo) * 128;

        if constexpr (ADD_F) {
            #pragma unroll
            for (int g = 0; g < 16; ++g) {
                U4 fv; fv.v = *(const uint4*)&fbuf[gbase + g * 8];
                #pragma unroll
                for (int j = 0; j < 8; ++j)
                    sv[g].h[j] = (_Float16)((float)sv[g].h[j] + (float)fv.h[j]);
            }
        } else {
            #pragma unroll
            for (int g = 0; g < 16; ++g)
                *(uint4*)&fbuf[gbase + g * 8] = sv[g].v;
        }

        float ring[17], zr[9], wsum = 0.f;
        #pragma unroll
        for (int i = 0; i < 17; ++i) ring[i] = 0.f;
        #pragma unroll
        for (int i = 0; i < 9; ++i) zr[i] = 0.f;
        U4 ob;
        #pragma unroll
        for (int c = 0; c < 136; ++c) {
            float z = 0.f;
            if (c < 128) {
                float v = (float)sv[c >> 3].h[c & 7];
                z = v > 0.f ? v : 0.f;
            }
            float zz = z * z;
            wsum += zz - ring[c % 17];
            ring[c % 17] = zz;
            zr[c % 9] = z;
            if (c >= 8) {
                int o = c - 8;
                float p75 = exp2f(-0.75f * log2f(wsum * KAPPA + 1.f));
                ob.h[o & 7] = (_Float16)(zr[(c + 1) % 9] * p75);
                if ((o & 7) == 7) *(uint4*)&outp[gbase + (o & ~7)] = ob.v;
            }
        }
    }
}

// ------------------------------- maxpool(3,2,1) 32 -> 16, 8 channels/thread
__global__ __launch_bounds__(256) void pool32v(const _Float16* __restrict__ in,
                                               _Float16* __restrict__ out)
{
    const int idx = blockIdx.x * 256 + threadIdx.x;   // 524288
    const int cg = idx & 15;
    const int opix = (idx >> 4) & 255;
    const int n = idx >> 12;
    const int oy = opix >> 4, ox = opix & 15;
    const _Float16* ib = in + (size_t)n * 1024 * 128 + cg * 8;
    float m[8] = {0.f, 0.f, 0.f, 0.f, 0.f, 0.f, 0.f, 0.f};
    #pragma unroll
    for (int dy = -1; dy <= 1; ++dy) {
        int iy = 2 * oy + dy;
        if ((unsigned)iy >= 32u) continue;
        #pragma unroll
        for (int dx = -1; dx <= 1; ++dx) {
            int ix = 2 * ox + dx;
            if ((unsigned)ix >= 32u) continue;
            U4 v; v.v = *(const uint4*)&ib[(size_t)(iy * 32 + ix) * 128];
            #pragma unroll
            for (int i = 0; i < 8; ++i) m[i] = fmaxf(m[i], (float)v.h[i]);
        }
    }
    U4 o;
    #pragma unroll
    for (int i = 0; i < 8; ++i) o.h[i] = (_Float16)m[i];
    *(uint4*)&out[((size_t)n * 256 + opix) * 128 + cg * 8] = o.v;
}

// ------------- maxpool(3,2,0)+global max == max over [0,15)^2, 8 ch/thread
__global__ __launch_bounds__(256) void gmax2(const _Float16* __restrict__ in,
                                             float* __restrict__ g)
{
    const int idx = blockIdx.x * 256 + threadIdx.x;   // 2048
    const int c8 = idx & 15;
    const int n = idx >> 4;
    const _Float16* ib = in + (size_t)n * 256 * 128 + c8 * 8;
    float m[8] = {0.f, 0.f, 0.f, 0.f, 0.f, 0.f, 0.f, 0.f};
    for (int y = 0; y < 15; ++y)
        #pragma unroll
        for (int x = 0; x < 15; ++x) {
            U4 v; v.v = *(const uint4*)&ib[(size_t)(y * 16 + x) * 128];
            #pragma unroll
            for (int i = 0; i < 8; ++i) m[i] = fmaxf(m[i], (float)v.h[i]);
        }
    float* gb = g + n * 128 + c8 * 8;
    *(float4*)&gb[0] = {m[0], m[1], m[2], m[3]};
    *(float4*)&gb[4] = {m[4], m[5], m[6], m[7]};
}

// ------------------------------------------------------------------- MLP
__global__ __launch_bounds__(256) void mlp_k(
    const float* __restrict__ g, const float* __restrict__ w,
    const float* __restrict__ b, float* __restrict__ out)
{
    const int idx = blockIdx.x * 256 + threadIdx.x;
    if (idx >= 1280) return;
    const int n = idx / 10, k = idx - n * 10;
    float acc = b[k];
    for (int c = 0; c < CCH; ++c) acc += g[n * CCH + c] * w[k * CCH + c];
    out[idx] = acc;
}

// ==================================================================== launch
extern "C" void kernel_launch(void* const* d_in, const int* in_sizes, int n_in,
                              void* d_out, int out_size, void* d_ws, size_t ws_size,
                              hipStream_t stream)
{
    const float* x   = (const float*)d_in[0];
    const float* w1  = (const float*)d_in[1];
    const float* b1  = (const float*)d_in[2];
    const float* bng = (const float*)d_in[3];
    const float* bnb = (const float*)d_in[4];
    const float* fw[4] = {(const float*)d_in[5],  (const float*)d_in[8],
                          (const float*)d_in[11], (const float*)d_in[14]};
    const float* fb[4] = {(const float*)d_in[6],  (const float*)d_in[9],
                          (const float*)d_in[12], (const float*)d_in[15]};
    const float* rw[4] = {(const float*)d_in[7],  (const float*)d_in[10],
                          (const float*)d_in[13], (const float*)d_in[16]};
    const float* mw = (const float*)d_in[17];
    const float* mb = (const float*)d_in[18];
    float* out = (float*)d_out;

    _Float16* ws16 = (_Float16*)d_ws;
    _Float16* buf0 = ws16;                       // [128][1024][128] ping
    _Float16* buf1 = ws16 + 16777216;            // pong
    _Float16* Fb32 = ws16 + 2 * 16777216;        // f persistence (32x32)
    _Float16* base3 = ws16 + 3 * 16777216;
    _Float16* A16a = base3;                      // [128][256][128] ping
    _Float16* A16b = base3 + 4194304;            // pong
    _Float16* F16  = base3 + 2 * 4194304;        // f persistence (16x16)
    _Float16* Wb   = base3 + 3 * 4194304;        // 8 x [9][128][128]
    float* stats = (float*)(Wb + 8 * 147456);
    float* scsh  = stats + 256;
    float* gm    = scsh + 256;
    _Float16* Pp = (_Float16*)(gm + 16384);      // [128][3][32][128] halo max

    zero_stats<<<1, 256, 0, stream>>>(stats);
    conv1_stats3<<<512, 256, 0, stream>>>(x, w1, b1, stats);
    bn_finalize<<<1, 128, 0, stream>>>(stats, bng, bnb, scsh);
    conv1_pool3<<<512, 256, 0, stream>>>(x, w1, b1, scsh, buf0, Pp);
    pool_fix<<<768, 256, 0, stream>>>(Pp, buf0);

    const float* lw[8] = {fw[0], rw[0], fw[1], rw[1], fw[2], rw[2], fw[3], rw[3]};
    for (int i = 0; i < 8; ++i)
        wcvt<<<576, 256, 0, stream>>>(lw[i], Wb + i * 147456);

    _Float16* cur = buf0;
    _Float16* alt = buf1;
    for (int s = 0; s < 2; ++s) {
        conv3f<32, false><<<512, 256, 0, stream>>>(cur, Wb + (2*s) * 147456, fb[s], Fb32, alt);
        { _Float16* t = cur; cur = alt; alt = t; }
        for (int it = 0; it < 3; ++it) {
            conv3f<32, true><<<512, 256, 0, stream>>>(cur, Wb + (2*s+1) * 147456, nullptr, Fb32, alt);
            { _Float16* t = cur; cur = alt; alt = t; }
        }
    }
    // 8 swaps -> cur == buf0
    pool32v<<<2048, 256, 0, stream>>>(cur, A16a);

    _Float16* cur16 = A16a;
    _Float16* alt16 = A16b;
    for (int s = 2; s < 4; ++s) {
        conv3f<16, false><<<256, 256, 0, stream>>>(cur16, Wb + (2*s) * 147456, fb[s], F16, alt16);
        { _Float16* t = cur16; cur16 = alt16; alt16 = t; }
        for (int it = 0; it < 3; ++it) {
            conv3f<16, true><<<256, 256, 0, stream>>>(cur16, Wb + (2*s+1) * 147456, nullptr, F16, alt16);
            { _Float16* t = cur16; cur16 = alt16; alt16 = t; }
        }
    }
    // 8 swaps -> cur16 == A16a
    gmax2<<<8, 256, 0, stream>>>(cur16, gm);
    mlp_k<<<5, 256, 0, stream>>>(gm, mw, mb, out);
}

// Round 6
// 1385.768 us; speedup vs baseline: 1.6188x; 1.3075x over previous
//
#include <hip/hip_runtime.h>

// RCNN forward. ALL convs on MFMA f16 (implicit GEMM); activations
// [n][y][x][c] f16. conv1 (5x5,3->128): MFMA K=75->3x32, fused BN-stats +
// raw-h maxpool (monotone: bn_g=1 => scale>0); BN+relu applied post-pool.
// conv3x3: fused banded-LRN epilogue.

#define CCH 128
constexpr float KAPPA = 0.001f / 17.0f;

typedef __attribute__((ext_vector_type(8))) _Float16 half8;
typedef __attribute__((ext_vector_type(4))) float f32x4;

union U4 { uint4 v; ushort us[8]; _Float16 h[8]; half8 f; };
union U2 { ushort4 u; _Float16 h[4]; };

// ---------------------------------------------------------------- zero stats
__global__ __launch_bounds__(256) void zero_stats(float* __restrict__ s) {
    s[threadIdx.x] = 0.f;
}

// -------------------- conv1 weight convert [128co][75] f32 -> [3kc][128co][32] f16
__global__ __launch_bounds__(256) void wcvt1(const float* __restrict__ wsrc,
                                             _Float16* __restrict__ wdst)
{
    const int idx = blockIdx.x * 256 + threadIdx.x;   // 12288
    const int kc = idx >> 12;
    const int rem = idx & 4095;
    const int co = rem >> 5;
    const int kk = rem & 31;
    const int k = kc * 32 + kk;
    wdst[idx] = (k < 75) ? (_Float16)wsrc[co * 75 + k] : (_Float16)0.f;
}

// ------------------- conv1 MFMA: stats + raw-h maxpool(3,2,1) in one kernel
// grid 2048 = 128 n x 16 strips of 4 h-rows. 4 waves; wave w = h-row y0+w,
// 64 px (4 tiles), all 128 co. K = 3 chunks of 32 (75 zero-padded).
__global__ __launch_bounds__(256, 2) void conv1m(
    const float* __restrict__ x, const _Float16* __restrict__ wc1,
    const float* __restrict__ bias, float* __restrict__ stats,
    _Float16* __restrict__ ph, _Float16* __restrict__ pp)
{
    __shared__ _Float16 xst[3 * 8 * 68];        // 6.5 KB staged input
    __shared__ _Float16 bnc[4 * 64 * 128];      // 64 KB h bounce [r][c][co^swz]
    __shared__ float ps[4][128], ps2[4][128];   // 4 KB stats partials

    const int bid = blockIdx.x;
    const int n = bid & 127;
    const int strip = bid >> 7;
    const int y0 = strip * 4;
    const int tid = threadIdx.x;
    const int w = tid >> 6, l = tid & 63;
    const int l15 = l & 15, lg = l >> 4;

    // stage x rows y0-2..y0+5 (halo'd), cols -2..65, f32 -> f16
    const float* xn = x + (size_t)n * 3 * 4096;
    for (int i = tid; i < 3 * 8 * 68; i += 256) {
        int ci = i / (8 * 68);
        int rm = i - ci * (8 * 68);
        int r = rm / 68, c = rm - r * 68;
        int gy = y0 - 2 + r, gx = c - 2;
        float v = ((unsigned)gy < 64u && (unsigned)gx < 64u)
                      ? xn[ci * 4096 + gy * 64 + gx] : 0.f;
        xst[i] = (_Float16)v;
    }

    f32x4 acc[8][4];
    #pragma unroll
    for (int cot = 0; cot < 8; ++cot) {
        f32x4 bv = *(const f32x4*)&bias[cot * 16 + lg * 4];
        #pragma unroll
        for (int pt = 0; pt < 4; ++pt) acc[cot][pt] = bv;
    }
    __syncthreads();

    #pragma unroll
    for (int kc = 0; kc < 3; ++kc) {
        int ba[8];
        #pragma unroll
        for (int j = 0; j < 8; ++j) {
            int k = kc * 32 + lg * 8 + j;
            k = k > 74 ? 74 : k;            // pad lanes: weight is 0 anyway
            int ci = k / 25;
            int r = k - ci * 25;
            int ky = r / 5;
            int kx = r - ky * 5;
            ba[j] = (ci * 8 + w + ky) * 68 + l15 + kx;
        }
        half8 bf[4];
        #pragma unroll
        for (int pt = 0; pt < 4; ++pt) {
            U4 bb;
            #pragma unroll
            for (int j = 0; j < 8; ++j) bb.h[j] = xst[ba[j] + pt * 16];
            bf[pt] = bb.f;
        }
        const _Float16* wk = wc1 + kc * 4096 + l15 * 32 + lg * 8;
        #pragma unroll
        for (int cot = 0; cot < 8; ++cot) {
            half8 av = *(const half8*)&wk[cot * 512];
            #pragma unroll
            for (int pt = 0; pt < 4; ++pt)
                acc[cot][pt] = __builtin_amdgcn_mfma_f32_16x16x32_f16(
                    av, bf[pt], acc[cot][pt], 0, 0, 0);
        }
    }

    // ---- per-wave per-co stats (exact f32, from acc)
    #pragma unroll
    for (int cot = 0; cot < 8; ++cot) {
        float s[4] = {0.f, 0.f, 0.f, 0.f}, s2[4] = {0.f, 0.f, 0.f, 0.f};
        #pragma unroll
        for (int pt = 0; pt < 4; ++pt)
            #pragma unroll
            for (int j = 0; j < 4; ++j) {
                float v = acc[cot][pt][j];
                s[j] += v; s2[j] += v * v;
            }
        #pragma unroll
        for (int o = 1; o < 16; o <<= 1)
            #pragma unroll
            for (int j = 0; j < 4; ++j) {
                s[j]  += __shfl_xor(s[j], o, 64);
                s2[j] += __shfl_xor(s2[j], o, 64);
            }
        if (l15 == 0) {
            #pragma unroll
            for (int j = 0; j < 4; ++j) {
                ps[w][cot * 16 + lg * 4 + j] = s[j];
                ps2[w][cot * 16 + lg * 4 + j] = s2[j];
            }
        }
    }

    // ---- bounce raw h -> LDS [r][c][co ^ ((c&7)*8)]
    #pragma unroll
    for (int cot = 0; cot < 8; ++cot)
        #pragma unroll
        for (int pt = 0; pt < 4; ++pt) {
            int c = pt * 16 + l15;
            int colx = (cot * 16 + lg * 4) ^ ((c & 7) * 8);
            U2 pk;
            pk.h[0] = (_Float16)acc[cot][pt][0];
            pk.h[1] = (_Float16)acc[cot][pt][1];
            pk.h[2] = (_Float16)acc[cot][pt][2];
            pk.h[3] = (_Float16)acc[cot][pt][3];
            *(ushort4*)&bnc[(w * 64 + c) * 128 + colx] = pk.u;
        }
    __syncthreads();

    if (tid < 128) {
        float A = ps[0][tid] + ps[1][tid] + ps[2][tid] + ps[3][tid];
        float B = ps2[0][tid] + ps2[1][tid] + ps2[2][tid] + ps2[3][tid];
        atomicAdd(&stats[tid], A);
        atomicAdd(&stats[tid + 128], B);
    }

    // ---- pool raw h (3x3, stride 2). oy = 2*strip + oysel.
    // oysel=0 misses its top halo row (prev strip's r=3) -> Pp + pool_fixr.
    constexpr float NEG = -3.0e38f;
    #pragma unroll
    for (int i = 0; i < 6; ++i) {
        int t = tid + i * 256;
        if (t < 1024) {
            int cg = t & 15, ox = (t >> 4) & 31, oysel = t >> 9;
            float m[8];
            #pragma unroll
            for (int j = 0; j < 8; ++j) m[j] = NEG;
            #pragma unroll
            for (int dy = 0; dy < 3; ++dy) {
                int r = 2 * oysel - 1 + dy;
                if (r < 0) continue;
                #pragma unroll
                for (int dx = 0; dx < 3; ++dx) {
                    int c = 2 * ox - 1 + dx;
                    if ((unsigned)c >= 64u) continue;
                    U4 v;
                    v.v = *(const uint4*)&bnc[(r * 64 + c) * 128 + ((cg * 8) ^ ((c & 7) * 8))];
                    #pragma unroll
                    for (int j = 0; j < 8; ++j) m[j] = fmaxf(m[j], (float)v.h[j]);
                }
            }
            U4 o;
            #pragma unroll
            for (int j = 0; j < 8; ++j) o.h[j] = (_Float16)m[j];
            int oy = strip * 2 + oysel;
            *(uint4*)&ph[((size_t)n * 1024 + oy * 32 + ox) * 128 + cg * 8] = o.v;
        } else if (strip < 15) {
            int t2 = t - 1024;                       // 0..511
            int cg = t2 & 15, ox = (t2 >> 4) & 31;
            float m[8];
            #pragma unroll
            for (int j = 0; j < 8; ++j) m[j] = NEG;
            #pragma unroll
            for (int dx = 0; dx < 3; ++dx) {
                int c = 2 * ox - 1 + dx;
                if ((unsigned)c >= 64u) continue;
                U4 v;
                v.v = *(const uint4*)&bnc[(3 * 64 + c) * 128 + ((cg * 8) ^ ((c & 7) * 8))];
                #pragma unroll
                for (int j = 0; j < 8; ++j) m[j] = fmaxf(m[j], (float)v.h[j]);
            }
            U4 o;
            #pragma unroll
            for (int j = 0; j < 8; ++j) o.h[j] = (_Float16)m[j];
            *(uint4*)&pp[(((size_t)n * 15 + strip) * 32 + ox) * 128 + cg * 8] = o.v;
        }
    }
}

// ------------- merge halo partials into pooled rows oy = 2s+2 (s=0..14)
__global__ __launch_bounds__(256) void pool_fixr(const _Float16* __restrict__ pp,
                                                 _Float16* __restrict__ ph)
{
    const int idx = blockIdx.x * 256 + threadIdx.x;   // 983040
    const int cg = idx & 15;
    const int ox = (idx >> 4) & 31;
    const int t = idx >> 9;
    const int s = t % 15;
    const int n = t / 15;
    const _Float16* p = pp + (((size_t)n * 15 + s) * 32 + ox) * 128 + cg * 8;
    _Float16* a = ph + ((size_t)n * 1024 + (2 * s + 2) * 32 + ox) * 128 + cg * 8;
    U4 av, bv;
    av.v = *(const uint4*)a;
    bv.v = *(const uint4*)p;
    #pragma unroll
    for (int j = 0; j < 8; ++j)
        if ((float)bv.h[j] > (float)av.h[j]) av.h[j] = bv.h[j];
    *(uint4*)a = av.v;
}

// --------------------------------------------------------------- bn finalize
__global__ __launch_bounds__(128) void bn_finalize(
    const float* __restrict__ stats, const float* __restrict__ g,
    const float* __restrict__ b, float* __restrict__ scsh)
{
    const int c = threadIdx.x;
    const float M = 128.f * 4096.f;
    float mean = stats[c] / M;
    float var = stats[c + 128] / M - mean * mean;
    float rstd = rsqrtf(var + 1e-5f);
    float sc = g[c] * rstd;
    scsh[c] = sc;
    scsh[c + 128] = b[c] - mean * sc;
}

// ------------------- BN + relu applied to pooled raw h (valid: scale > 0)
__global__ __launch_bounds__(256) void bnrelu(
    const _Float16* __restrict__ ph, const float* __restrict__ scsh,
    _Float16* __restrict__ out)
{
    const int idx = blockIdx.x * 256 + threadIdx.x;   // 2097152
    const int cg = idx & 15;
    const size_t e = (size_t)(idx >> 4) * 128 + cg * 8;
    U4 v; v.v = *(const uint4*)&ph[e];
    U4 o;
    #pragma unroll
    for (int j = 0; j < 8; ++j) {
        int co = cg * 8 + j;
        float f = (float)v.h[j] * scsh[co] + scsh[co + 128];
        o.h[j] = (_Float16)fmaxf(f, 0.f);
    }
    *(uint4*)&out[e] = o.v;
}

// --------------------------------------- weight convert fp32 [co][ci][3][3]
//                                      -> f16 [tap][co][ci]
__global__ __launch_bounds__(256) void wcvt(const float* __restrict__ wsrc,
                                            _Float16* __restrict__ wdst)
{
    const int idx = blockIdx.x * 256 + threadIdx.x;   // 147456
    const int t = idx >> 14;
    const int rem = idx & 16383;
    const int co = rem >> 7;
    const int ci = rem & 127;
    wdst[idx] = (_Float16)wsrc[(co * 128 + ci) * 9 + t];
}

// ------------------------ conv3x3 MFMA (128->128, pad 1) + FUSED banded LRN
template<int H, bool ADD_F>
__global__ __launch_bounds__(256, 2) void conv3f(
    const _Float16* __restrict__ in, const _Float16* __restrict__ wb,
    const float* __restrict__ bias, _Float16* __restrict__ fbuf,
    _Float16* __restrict__ outp)
{
    constexpr int W = H, HW = H * W;
    constexpr int XP = W + 2;
    constexpr int PITCH = 40;
    constexpr int ROWS = 10;
    constexpr int PTN = (H == 32) ? 4 : 2;
    constexpr int NPIX = PTN * 16;
    constexpr int STAGE = ROWS * XP * PITCH;
    constexpr int TASKS = ROWS * W * 4;
    constexpr int NIT = (TASKS + 255) / 256;
    constexpr int LOG4W = (H == 32) ? 7 : 6;
    constexpr int LDSH = 4 * NPIX * 128;

    __shared__ _Float16 xs[LDSH];

    const int bid = blockIdx.x;
    const int slot = bid >> 3;
    const int n = (bid & 7) + 8 * (slot & 15);
    const int y0 = (slot >> 4) * 8;
    const int tid = threadIdx.x;
    const int w = tid >> 6, l = tid & 63;
    const int l15 = l & 15, lg = l >> 4;

    for (int i = tid; i < STAGE / 2; i += 256) ((uint*)xs)[i] = 0;

    f32x4 acc[8][PTN];
    #pragma unroll
    for (int cot = 0; cot < 8; ++cot) {
        f32x4 bv = {0.f, 0.f, 0.f, 0.f};
        if constexpr (!ADD_F) bv = *(const f32x4*)&bias[cot * 16 + lg * 4];
        #pragma unroll
        for (int pt = 0; pt < PTN; ++pt) acc[cot][pt] = bv;
    }

    const _Float16* inb = in + (size_t)n * HW * 128;
    uint4 stg[NIT];

    auto issue = [&](int c0) {
        #pragma unroll
        for (int i = 0; i < NIT; ++i) {
            int t = tid + i * 256;
            uint4 v = {0u, 0u, 0u, 0u};
            if (TASKS % 256 == 0 || t < TASKS) {
                int g = t & 3, xx = (t >> 2) & (W - 1), yl = t >> LOG4W;
                int gy = y0 - 1 + yl;
                if ((unsigned)gy < (unsigned)H)
                    v = *(const uint4*)&inb[((size_t)(gy * W + xx)) * 128 + c0 + g * 8];
            }
            stg[i] = v;
        }
    };
    auto commit = [&]() {
        #pragma unroll
        for (int i = 0; i < NIT; ++i) {
            int t = tid + i * 256;
            if (TASKS % 256 == 0 || t < TASKS) {
                int g = t & 3, xx = (t >> 2) & (W - 1), yl = t >> LOG4W;
                *(uint4*)&xs[(yl * XP + xx + 1) * PITCH + g * 8] = stg[i];
            }
        }
    };

    int bofs[PTN];
    #pragma unroll
    for (int pt = 0; pt < PTN; ++pt) {
        int row_l = 2 * w + ((H == 32) ? (pt >> 1) : pt);
        int xb = ((H == 32) ? (pt & 1) * 16 : 0) + l15;
        bofs[pt] = ((row_l + 1) * XP + xb + 1) * PITCH + lg * 8;
    }
    const _Float16* wl = wb + l15 * 128 + lg * 8;

    issue(0);
    for (int cc = 0; cc < 4; ++cc) {
        const int c0 = cc * 32;
        __syncthreads();
        commit();
        if (cc < 3) issue(c0 + 32);
        __syncthreads();
        #pragma unroll
        for (int ky = -1; ky <= 1; ++ky)
            #pragma unroll
            for (int kx = -1; kx <= 1; ++kx) {
                const int t9 = (ky + 1) * 3 + (kx + 1);
                half8 bf[PTN];
                #pragma unroll
                for (int pt = 0; pt < PTN; ++pt)
                    bf[pt] = *(const half8*)&xs[bofs[pt] + (ky * XP + kx) * PITCH];
                const _Float16* wt = wl + t9 * 16384 + c0;
                #pragma unroll
                for (int coh = 0; coh < 2; ++coh) {
                    half8 av[4];
                    #pragma unroll
                    for (int j = 0; j < 4; ++j)
                        av[j] = *(const half8*)&wt[(coh * 4 + j) * 2048];
                    #pragma unroll
                    for (int j = 0; j < 4; ++j)
                        #pragma unroll
                        for (int pt = 0; pt < PTN; ++pt)
                            acc[coh * 4 + j][pt] = __builtin_amdgcn_mfma_f32_16x16x32_f16(
                                av[j], bf[pt], acc[coh * 4 + j][pt], 0, 0, 0);
                }
            }
    }

    // ---------------- fused epilogue: bounce -> per-pixel LRN ----------------
    __syncthreads();
    _Float16* bx = xs + w * (NPIX * 128);
    #pragma unroll
    for (int a = 0; a < 8; ++a)
        #pragma unroll
        for (int pt = 0; pt < PTN; ++pt) {
            const int wpx = pt * 16 + l15;
            const int col = (a * 16 + lg * 4) ^ ((wpx & 7) * 8);
            U2 pk;
            pk.h[0] = (_Float16)acc[a][pt][0];
            pk.h[1] = (_Float16)acc[a][pt][1];
            pk.h[2] = (_Float16)acc[a][pt][2];
            pk.h[3] = (_Float16)acc[a][pt][3];
            *(ushort4*)&bx[wpx * 128 + col] = pk.u;
        }
    __syncthreads();

    if (H == 32 || l < 32) {
        const int px = l & (NPIX - 1);
        const int p3 = px & 7;
        U4 sv[16];
        #pragma unroll
        for (int g = 0; g < 16; ++g)
            sv[g].v = *(const uint4*)&bx[px * 128 + ((g ^ p3) * 8)];

        const int row_l = 2 * w + ((H == 32) ? (px >> 5) : (px >> 4));
        const int xo = px & (W - 1);
        const size_t gbase = ((size_t)n * HW + (size_t)(y0 + row_l) * W + xo) * 128;

        if constexpr (ADD_F) {
            #pragma unroll
            for (int g = 0; g < 16; ++g) {
                U4 fv; fv.v = *(const uint4*)&fbuf[gbase + g * 8];
                #pragma unroll
                for (int j = 0; j < 8; ++j)
                    sv[g].h[j] = (_Float16)((float)sv[g].h[j] + (float)fv.h[j]);
            }
        } else {
            #pragma unroll
            for (int g = 0; g < 16; ++g)
                *(uint4*)&fbuf[gbase + g * 8] = sv[g].v;
        }

        float ring[17], zr[9], wsum = 0.f;
        #pragma unroll
        for (int i = 0; i < 17; ++i) ring[i] = 0.f;
        #pragma unroll
        for (int i = 0; i < 9; ++i) zr[i] = 0.f;
        U4 ob;
        #pragma unroll
        for (int c = 0; c < 136; ++c) {
            float z = 0.f;
            if (c < 128) {
                float v = (float)sv[c >> 3].h[c & 7];
                z = v > 0.f ? v : 0.f;
            }
            float zz = z * z;
            wsum += zz - ring[c % 17];
            ring[c % 17] = zz;
            zr[c % 9] = z;
            if (c >= 8) {
                int o = c - 8;
                float p75 = exp2f(-0.75f * log2f(wsum * KAPPA + 1.f));
                ob.h[o & 7] = (_Float16)(zr[(c + 1) % 9] * p75);
                if ((o & 7) == 7) *(uint4*)&outp[gbase + (o & ~7)] = ob.v;
            }
        }
    }
}

// ------------------------------- maxpool(3,2,1) 32 -> 16, 8 channels/thread
__global__ __launch_bounds__(256) void pool32v(const _Float16* __restrict__ in,
                                               _Float16* __restrict__ out)
{
    const int idx = blockIdx.x * 256 + threadIdx.x;   // 524288
    const int cg = idx & 15;
    const int opix = (idx >> 4) & 255;
    const int n = idx >> 12;
    const int oy = opix >> 4, ox = opix & 15;
    const _Float16* ib = in + (size_t)n * 1024 * 128 + cg * 8;
    float m[8] = {0.f, 0.f, 0.f, 0.f, 0.f, 0.f, 0.f, 0.f};
    #pragma unroll
    for (int dy = -1; dy <= 1; ++dy) {
        int iy = 2 * oy + dy;
        if ((unsigned)iy >= 32u) continue;
        #pragma unroll
        for (int dx = -1; dx <= 1; ++dx) {
            int ix = 2 * ox + dx;
            if ((unsigned)ix >= 32u) continue;
            U4 v; v.v = *(const uint4*)&ib[(size_t)(iy * 32 + ix) * 128];
            #pragma unroll
            for (int i = 0; i < 8; ++i) m[i] = fmaxf(m[i], (float)v.h[i]);
        }
    }
    U4 o;
    #pragma unroll
    for (int i = 0; i < 8; ++i) o.h[i] = (_Float16)m[i];
    *(uint4*)&out[((size_t)n * 256 + opix) * 128 + cg * 8] = o.v;
}

// ------------- maxpool(3,2,0)+global max == max over [0,15)^2, 8 ch/thread
__global__ __launch_bounds__(256) void gmax2(const _Float16* __restrict__ in,
                                             float* __restrict__ g)
{
    const int idx = blockIdx.x * 256 + threadIdx.x;   // 2048
    const int c8 = idx & 15;
    const int n = idx >> 4;
    const _Float16* ib = in + (size_t)n * 256 * 128 + c8 * 8;
    float m[8] = {0.f, 0.f, 0.f, 0.f, 0.f, 0.f, 0.f, 0.f};
    for (int y = 0; y < 15; ++y)
        #pragma unroll
        for (int x = 0; x < 15; ++x) {
            U4 v; v.v = *(const uint4*)&ib[(size_t)(y * 16 + x) * 128];
            #pragma unroll
            for (int i = 0; i < 8; ++i) m[i] = fmaxf(m[i], (float)v.h[i]);
        }
    float* gb = g + n * 128 + c8 * 8;
    *(float4*)&gb[0] = {m[0], m[1], m[2], m[3]};
    *(float4*)&gb[4] = {m[4], m[5], m[6], m[7]};
}

// ------------------------------------------------------------------- MLP
__global__ __launch_bounds__(256) void mlp_k(
    const float* __restrict__ g, const float* __restrict__ w,
    const float* __restrict__ b, float* __restrict__ out)
{
    const int idx = blockIdx.x * 256 + threadIdx.x;
    if (idx >= 1280) return;
    const int n = idx / 10, k = idx - n * 10;
    float acc = b[k];
    for (int c = 0; c < CCH; ++c) acc += g[n * CCH + c] * w[k * CCH + c];
    out[idx] = acc;
}

// ==================================================================== launch
extern "C" void kernel_launch(void* const* d_in, const int* in_sizes, int n_in,
                              void* d_out, int out_size, void* d_ws, size_t ws_size,
                              hipStream_t stream)
{
    const float* x   = (const float*)d_in[0];
    const float* w1  = (const float*)d_in[1];
    const float* b1  = (const float*)d_in[2];
    const float* bng = (const float*)d_in[3];
    const float* bnb = (const float*)d_in[4];
    const float* fw[4] = {(const float*)d_in[5],  (const float*)d_in[8],
                          (const float*)d_in[11], (const float*)d_in[14]};
    const float* fb[4] = {(const float*)d_in[6],  (const float*)d_in[9],
                          (const float*)d_in[12], (const float*)d_in[15]};
    const float* rw[4] = {(const float*)d_in[7],  (const float*)d_in[10],
                          (const float*)d_in[13], (const float*)d_in[16]};
    const float* mw = (const float*)d_in[17];
    const float* mb = (const float*)d_in[18];
    float* out = (float*)d_out;

    _Float16* ws16 = (_Float16*)d_ws;
    _Float16* buf0 = ws16;                       // [128][1024][128] ping
    _Float16* buf1 = ws16 + 16777216;            // pong; also PH (pooled raw h)
    _Float16* Fb32 = ws16 + 2 * 16777216;        // f persistence (32x32)
    _Float16* base3 = ws16 + 3 * 16777216;
    _Float16* A16a = base3;                      // [128][256][128] ping
    _Float16* A16b = base3 + 4194304;            // pong
    _Float16* F16  = base3 + 2 * 4194304;        // f persistence (16x16)
    _Float16* Wb   = base3 + 3 * 4194304;        // 8 x [9][128][128]
    float* stats = (float*)(Wb + 8 * 147456);
    float* scsh  = stats + 256;
    float* gm    = scsh + 256;
    _Float16* Pp  = (_Float16*)(gm + 16384);     // [128][15][32][128] halo max
    _Float16* Wc1 = Pp + 7864320;                // [3][128][32]
    _Float16* PH  = buf1;

    zero_stats<<<1, 256, 0, stream>>>(stats);
    wcvt1<<<48, 256, 0, stream>>>(w1, Wc1);
    conv1m<<<2048, 256, 0, stream>>>(x, Wc1, b1, stats, PH, Pp);
    pool_fixr<<<3840, 256, 0, stream>>>(Pp, PH);
    bn_finalize<<<1, 128, 0, stream>>>(stats, bng, bnb, scsh);
    bnrelu<<<8192, 256, 0, stream>>>(PH, scsh, buf0);

    const float* lw[8] = {fw[0], rw[0], fw[1], rw[1], fw[2], rw[2], fw[3], rw[3]};
    for (int i = 0; i < 8; ++i)
        wcvt<<<576, 256, 0, stream>>>(lw[i], Wb + i * 147456);

    _Float16* cur = buf0;
    _Float16* alt = buf1;
    for (int s = 0; s < 2; ++s) {
        conv3f<32, false><<<512, 256, 0, stream>>>(cur, Wb + (2*s) * 147456, fb[s], Fb32, alt);
        { _Float16* t = cur; cur = alt; alt = t; }
        for (int it = 0; it < 3; ++it) {
            conv3f<32, true><<<512, 256, 0, stream>>>(cur, Wb + (2*s+1) * 147456, nullptr, Fb32, alt);
            { _Float16* t = cur; cur = alt; alt = t; }
        }
    }
    // 8 swaps -> cur == buf0
    pool32v<<<2048, 256, 0, stream>>>(cur, A16a);

    _Float16* cur16 = A16a;
    _Float16* alt16 = A16b;
    for (int s = 2; s < 4; ++s) {
        conv3f<16, false><<<256, 256, 0, stream>>>(cur16, Wb + (2*s) * 147456, fb[s], F16, alt16);
        { _Float16* t = cur16; cur16 = alt16; alt16 = t; }
        for (int it = 0; it < 3; ++it) {
            conv3f<16, true><<<256, 256, 0, stream>>>(cur16, Wb + (2*s+1) * 147456, nullptr, F16, alt16);
            { _Float16* t = cur16; cur16 = alt16; alt16 = t; }
        }
    }
    // 8 swaps -> cur16 == A16a
    gmax2<<<8, 256, 0, stream>>>(cur16, gm);
    mlp_k<<<5, 256, 0, stream>>>(gm, mw, mb, out);
}